// Round 9
// baseline (138.525 us; speedup 1.0000x reference)
//
#include <hip/hip_runtime.h>
#include <hip/hip_bf16.h>
#include <hip/hip_cooperative_groups.h>

namespace cg = cooperative_groups;

// Problem constants
#define Bn   4
#define Cn   256
#define Dn   32
#define Hn   64
#define Wn   64
#define Kt   64          // top-k
#define PROJ 512
#define DHW  (Dn*Hn*Wn)  // 131072
#define HW   (Hn*Wn)     // 4096
#define VECLEN (Kt*Cn)   // 16384 per batch

#define NBIN    4096     // fallback histogram bins (top 12 sortable bits)
#define CANDMAX 4096     // fallback candidate cap
#define SLOT    128      // per-compact-block slot stride (u64): [0]=count, 127 usable
#define STATIC_THR 3.0f  // scores ~ N(0,1); top-64/131072 is ~3.24 sigma.
                         // >3.0 keeps ~177/batch. If ever wrong (any block >127
                         // cands, or total <64 or >4096), phase B recomputes
                         // exactly -- correctness never depends on the guess.

// ---- workspace layout (bytes) ----
#define WS_CAND_OFF 0            // u64 cand[Bn*64][SLOT] = 256 KB
#define WS_IDX_OFF  (256*1024)   // int topk_idx[Bn*Kt]   = 1 KB
#define WS_VEC_OFF  (260*1024)   // float vec[Bn][VECLEN] = 256 KB

// ---- d_out layout (float32 elements) ----
#define OUT_SCORES 768
#define OUT_FEAT   1024

__device__ __forceinline__ unsigned f2sortable(float f) {
    unsigned u = __float_as_uint(f);
    return (u & 0x80000000u) ? ~u : (u | 0x80000000u);
}
__device__ __forceinline__ float sortable2f(unsigned u) {
    unsigned orig = (u & 0x80000000u) ? (u & 0x7FFFFFFFu) : ~u;
    return __uint_as_float(orig);
}

// ---------------- Fused: compact | top-k | gather | gemv ------------------
// grid = 256 blocks x 256 threads, cooperative; grid.sync between phases.
__global__ __launch_bounds__(256) void fused_kernel(
        const float* __restrict__ fm, const float* __restrict__ score,
        const float* __restrict__ Wp, const float* __restrict__ bias,
        float* __restrict__ out, unsigned long long* __restrict__ cand,
        int* __restrict__ topk_idx, float* __restrict__ vec) {
    cg::grid_group grid = cg::this_grid();
    const int blk = blockIdx.x;        // 0..255
    const int tid = threadIdx.x;       // 0..255

    __shared__ unsigned long long keys[CANDMAX];   // 32 KB (B)
    __shared__ unsigned long long win[Kt];
    __shared__ int lh[NBIN];                       // 16 KB (B fallback)
    __shared__ int partial[256];
    __shared__ int cnts[64], offs[64];
    __shared__ int s_n, s_thr, s_cnt, s_ovf;
    __shared__ unsigned long long lc[SLOT - 1];    // (A)
    __shared__ int lcnt;
    __shared__ float gred[4][8];                   // (D)

    // ================= Phase A: static-threshold compact =================
    {
        const int b   = blk >> 6;
        const int sub = blk & 63;
        if (tid == 0) lcnt = 0;
        __syncthreads();

        const unsigned thr = f2sortable(STATIC_THR);
        const float4* src = (const float4*)(score + (size_t)b * DHW) + sub * 512;
        #pragma unroll
        for (int i = tid; i < 512; i += 256) {
            float4 v = src[i];
            unsigned gbase = (unsigned)((sub * 512 + i) * 4);
            float vals[4] = {v.x, v.y, v.z, v.w};
            #pragma unroll
            for (int l = 0; l < 4; ++l) {
                unsigned u = f2sortable(vals[l]);
                if (u >= thr) {
                    int pos = atomicAdd(&lcnt, 1);
                    if (pos < SLOT - 1)
                        lc[pos] = ((unsigned long long)u << 32) |
                                  (0xFFFFFFFFu - (gbase + l));
                }
            }
        }
        __syncthreads();

        unsigned long long* cb = cand + (size_t)blk * SLOT;
        int n = lcnt;
        if (n > SLOT - 1) n = SLOT;          // SLOT = overflow marker
        if (tid == 0) cb[0] = (unsigned long long)n;
        int m = (n > SLOT - 1) ? (SLOT - 1) : n;
        for (int i = tid; i < m; i += 256) cb[1 + i] = lc[i];
    }
    grid.sync();

    // ================= Phase B: rank-select top-64 (blocks 0..3) =========
    if (blk < Bn) {
        const int b = blk;
        if (tid == 0) { s_ovf = 0; s_cnt = 0; }
        __syncthreads();
        if (tid < 64) {
            int c = (int)cand[(size_t)((b << 6) + tid) * SLOT];
            if (c > SLOT - 1) atomicOr(&s_ovf, 1);
            cnts[tid] = c;
        }
        __syncthreads();
        if (tid == 0) {
            int o = 0;
            for (int s = 0; s < 64; ++s) { offs[s] = o; o += cnts[s]; }
            s_n = o;
        }
        __syncthreads();

        int n = s_n;
        if (!s_ovf && n >= Kt && n <= CANDMAX) {
            for (int s = 0; s < 64; ++s) {
                int c = cnts[s], o = offs[s];
                const unsigned long long* cb =
                    cand + (size_t)((b << 6) + s) * SLOT + 1;
                for (int i = tid; i < c; i += 256) keys[o + i] = cb[i];
            }
            __syncthreads();
        } else {
            // ---- exact fallback: hist -> threshold -> compact ----
            for (int i = tid; i < NBIN; i += 256) lh[i] = 0;
            __syncthreads();
            const float4* src = (const float4*)(score + (size_t)b * DHW);
            for (int i = tid; i < DHW / 4; i += 256) {
                float4 v = src[i];
                atomicAdd(&lh[f2sortable(v.x) >> 20], 1);
                atomicAdd(&lh[f2sortable(v.y) >> 20], 1);
                atomicAdd(&lh[f2sortable(v.z) >> 20], 1);
                atomicAdd(&lh[f2sortable(v.w) >> 20], 1);
            }
            __syncthreads();
            {
                int base = NBIN - 16 - 16 * tid;
                int s = 0;
                #pragma unroll
                for (int i = 0; i < 16; ++i) s += lh[base + i];
                partial[tid] = s;
            }
            __syncthreads();
            if (tid == 0) {
                int cum = 0, T = 0;
                for (int j = 0; j < 256; ++j) {
                    if (cum + partial[j] >= Kt) {
                        int bb = NBIN - 1 - 16 * j;
                        for (int i = 0; i < 16; ++i) {
                            cum += lh[bb - i];
                            if (cum >= Kt) { T = bb - i; break; }
                        }
                        break;
                    }
                    cum += partial[j];
                }
                s_thr = T;
            }
            __syncthreads();
            const unsigned thr = (unsigned)s_thr;
            for (int i = tid; i < DHW / 4; i += 256) {
                float4 v = src[i];
                float vals[4] = {v.x, v.y, v.z, v.w};
                #pragma unroll
                for (int l = 0; l < 4; ++l) {
                    unsigned u = f2sortable(vals[l]);
                    if ((u >> 20) >= thr) {
                        int pos = atomicAdd(&s_cnt, 1);
                        if (pos < CANDMAX)
                            keys[pos] = ((unsigned long long)u << 32) |
                                        (0xFFFFFFFFu - (unsigned)(4 * i + l));
                    }
                }
            }
            __syncthreads();
            n = s_cnt;
            if (n > CANDMAX) n = CANDMAX;
        }

        // rank selection: unique keys -> unique ranks; n >= 64
        for (int i = tid; i < n; i += 256) {
            unsigned long long k = keys[i];
            int r = 0;
            for (int j = 0; j < n; ++j) r += (keys[j] > k);
            if (r < Kt) win[r] = k;
        }
        __syncthreads();

        if (tid < Kt) {
            unsigned long long kk = win[tid];
            float sc = sortable2f((unsigned)(kk >> 32));
            unsigned gidx = 0xFFFFFFFFu - (unsigned)(kk & 0xFFFFFFFFu);
            int z = (int)(gidx >> 12);
            int y = (int)((gidx >> 6) & 63);
            int x = (int)(gidx & 63);
            int o = (b * Kt + tid) * 3;
            out[o + 0] = (float)z;
            out[o + 1] = (float)y;
            out[o + 2] = (float)x;
            out[OUT_SCORES + b * Kt + tid] = sc;
            topk_idx[b * Kt + tid] = (int)gidx;
        }
    }
    grid.sync();

    // ================= Phase C: gather (lane = k, deep MLP) ==============
    {
        const int b   = blk >> 6;
        const int cg_ = blk & 63;
        const int k   = tid & 63;          // lane = k
        const int c   = cg_ * 4 + (tid >> 6);

        const int idx = topk_idx[b * Kt + k];
        const int z = idx >> 12;
        const int y = (idx >> 6) & 63;
        const int x = idx & 63;
        const int z0 = max(z - 2, 0), y0 = max(y - 2, 0), x0 = max(x - 2, 0);
        const int nz = min(5, Dn - z0), ny = min(5, Hn - y0), nx = min(5, Wn - x0);
        const int xe = x0 + nx;            // <= 64
        const int a0 = x0 & ~3;
        const bool need2 = (a0 + 4) < xe;

        float m[8];
        #pragma unroll
        for (int j = 0; j < 8; ++j) {
            int e = a0 + j;
            m[j] = (e >= x0 && e < xe) ? 1.f : 0.f;
        }

        const float* base = fm + ((size_t)(b * Cn + c)) * DHW
                               + (size_t)z0 * HW + (size_t)y0 * Wn;
        float s = 0.f;
        #pragma unroll
        for (int iz = 0; iz < 5; ++iz) {
            #pragma unroll
            for (int iy = 0; iy < 5; ++iy) {
                if (iz < nz && iy < ny) {          // per-lane predication
                    const float* row = base + iz * HW + iy * Wn;
                    float4 v0 = *(const float4*)(row + a0);
                    s = fmaf(v0.x, m[0], s);
                    s = fmaf(v0.y, m[1], s);
                    s = fmaf(v0.z, m[2], s);
                    s = fmaf(v0.w, m[3], s);
                    if (need2) {
                        float4 v1 = *(const float4*)(row + a0 + 4);
                        s = fmaf(v1.x, m[4], s);
                        s = fmaf(v1.y, m[5], s);
                        s = fmaf(v1.z, m[6], s);
                        s = fmaf(v1.w, m[7], s);
                    }
                }
            }
        }
        vec[((size_t)(b * Kt + k) << 8) + c] = s / (float)(nz * ny * nx);
    }
    grid.sync();

    // ================= Phase D: GEMV, 2 Wp rows per block ================
    {
        const int p0 = blk * 2;            // p0, p0+1
        const float4* w0 = (const float4*)(Wp + (size_t)p0 * VECLEN);
        const float4* w1 = (const float4*)(Wp + (size_t)(p0 + 1) * VECLEN);

        float acc0[Bn] = {0.f, 0.f, 0.f, 0.f};
        float acc1[Bn] = {0.f, 0.f, 0.f, 0.f};
        for (int i = tid; i < VECLEN / 4; i += 256) {
            float4 a = w0[i];
            float4 c = w1[i];
            #pragma unroll
            for (int bb = 0; bb < Bn; ++bb) {
                float4 vv = ((const float4*)(vec + bb * VECLEN))[i];
                acc0[bb] += a.x * vv.x + a.y * vv.y + a.z * vv.z + a.w * vv.w;
                acc1[bb] += c.x * vv.x + c.y * vv.y + c.z * vv.z + c.w * vv.w;
            }
        }

        const int lane = tid & 63, wave = tid >> 6;
        #pragma unroll
        for (int bb = 0; bb < Bn; ++bb) {
            float v0 = acc0[bb], v1 = acc1[bb];
            #pragma unroll
            for (int off = 32; off > 0; off >>= 1) {
                v0 += __shfl_down(v0, off, 64);
                v1 += __shfl_down(v1, off, 64);
            }
            if (lane == 0) { gred[wave][bb * 2] = v0; gred[wave][bb * 2 + 1] = v1; }
        }
        __syncthreads();
        if (tid < 8) {
            int bb = tid >> 1, q = tid & 1;
            float t = gred[0][tid] + gred[1][tid] + gred[2][tid] + gred[3][tid];
            out[OUT_FEAT + bb * PROJ + p0 + q] = t + bias[p0 + q];
        }
    }
}

extern "C" void kernel_launch(void* const* d_in, const int* in_sizes, int n_in,
                              void* d_out, int out_size, void* d_ws, size_t ws_size,
                              hipStream_t stream) {
    const float* fm    = (const float*)d_in[0];
    const float* score = (const float*)d_in[1];
    const float* Wp    = (const float*)d_in[2];
    const float* bias  = (const float*)d_in[3];
    float* out = (float*)d_out;

    char* ws = (char*)d_ws;
    unsigned long long* cand = (unsigned long long*)(ws + WS_CAND_OFF);
    int*   topk_idx = (int*)(ws + WS_IDX_OFF);
    float* vec      = (float*)(ws + WS_VEC_OFF);

    void* args[] = { (void*)&fm, (void*)&score, (void*)&Wp, (void*)&bias,
                     (void*)&out, (void*)&cand, (void*)&topk_idx, (void*)&vec };
    hipLaunchCooperativeKernel((const void*)fused_kernel, dim3(256), dim3(256),
                               args, 0, stream);
}

// Round 10
// 65.535 us; speedup vs baseline: 2.1137x; 2.1137x over previous
//
#include <hip/hip_runtime.h>
#include <hip/hip_bf16.h>

// Problem constants
#define Bn   4
#define Cn   256
#define Dn   32
#define Hn   64
#define Wn   64
#define Kt   64          // top-k
#define PROJ 512
#define DHW  (Dn*Hn*Wn)  // 131072
#define HW   (Hn*Wn)     // 4096
#define VECLEN (Kt*Cn)   // 16384 per batch

#define NBIN    4096     // fallback histogram bins (top 12 sortable bits)
#define CANDMAX 4096     // fallback candidate cap
#define SLOT    128      // per-compact-block slot stride (u64): [0]=count, 127 usable
#define STATIC_THR 3.0f  // scores ~ N(0,1); top-64/131072 is ~3.24 sigma.
                         // >3.0 keeps ~177/batch. If ever wrong (any block >127
                         // cands, or total <64 or >4096), final_kernel recomputes
                         // exactly -- correctness never depends on the guess.

// ---- workspace layout (bytes) ----
#define WS_CAND_OFF 0            // u64 cand[Bn*64][SLOT] = 256 KB
#define WS_IDX_OFF  (256*1024)   // int sorted_idx[Bn*Kt] = 1 KB ((korig<<20)|gidx, spatial order)
#define WS_VEC_OFF  (260*1024)   // float vec[Bn][VECLEN] = 256 KB

// ---- d_out layout (float32 elements) ----
#define OUT_SCORES 768
#define OUT_FEAT   1024

__device__ __forceinline__ unsigned f2sortable(float f) {
    unsigned u = __float_as_uint(f);
    return (u & 0x80000000u) ? ~u : (u | 0x80000000u);
}
__device__ __forceinline__ float sortable2f(unsigned u) {
    unsigned orig = (u & 0x80000000u) ? (u & 0x7FFFFFFFu) : ~u;
    return __uint_as_float(orig);
}

// ---------------- Pass 1: static-threshold compact into per-block slots --
// grid = Bn*64 = 256 blocks x 256 threads; block owns slot region [blk*SLOT].
// Every block writes its count word unconditionally -> no pre-zero needed.
__global__ __launch_bounds__(256) void compact_kernel(
        const float* __restrict__ score, unsigned long long* __restrict__ cand) {
    __shared__ unsigned long long lc[SLOT - 1];
    __shared__ int lcnt;
    const int blk = blockIdx.x;
    const int b   = blk >> 6;
    const int sub = blk & 63;
    const int tid = threadIdx.x;
    if (tid == 0) lcnt = 0;
    __syncthreads();

    const unsigned thr = f2sortable(STATIC_THR);
    const float4* src = (const float4*)(score + (size_t)b * DHW) + sub * 512;
    #pragma unroll
    for (int i = tid; i < 512; i += 256) {
        float4 v = src[i];
        unsigned gbase = (unsigned)((sub * 512 + i) * 4);
        float vals[4] = {v.x, v.y, v.z, v.w};
        #pragma unroll
        for (int l = 0; l < 4; ++l) {
            unsigned u = f2sortable(vals[l]);
            if (u >= thr) {
                int pos = atomicAdd(&lcnt, 1);
                if (pos < SLOT - 1)
                    lc[pos] = ((unsigned long long)u << 32) |
                              (0xFFFFFFFFu - (gbase + l));
            }
        }
    }
    __syncthreads();

    unsigned long long* cb = cand + (size_t)blk * SLOT;
    int n = lcnt;
    if (n > SLOT - 1) n = SLOT;          // SLOT = overflow marker
    if (tid == 0) cb[0] = (unsigned long long)n;
    int m = (n > SLOT - 1) ? (SLOT - 1) : n;
    for (int i = tid; i < m; i += 256) cb[1 + i] = lc[i];
}

// ---------------- Pass 2: rank-select top-64 (w/ exact fallback) ---------
// Emits: centers+scores to out, and a SPATIALLY SORTED gather list:
// sorted_idx[b*64 + r] = (korig << 20) | gidx, r = rank of gidx ascending.
__global__ __launch_bounds__(256) void final_kernel(
        const float* __restrict__ score,
        const unsigned long long* __restrict__ cand,
        float* __restrict__ out, int* __restrict__ sorted_idx) {
    __shared__ unsigned long long keys[CANDMAX];   // 32 KB
    __shared__ unsigned long long win[Kt];
    __shared__ unsigned sgidx[Kt];
    __shared__ int lh[NBIN];                       // 16 KB (fallback only)
    __shared__ int partial[256];
    __shared__ int cnts[64], offs[64];
    __shared__ int s_n, s_thr, s_cnt, s_ovf;
    const int b   = blockIdx.x;
    const int tid = threadIdx.x;

    if (tid == 0) { s_ovf = 0; s_cnt = 0; }
    __syncthreads();
    if (tid < 64) {
        int c = (int)cand[(size_t)((b << 6) + tid) * SLOT];
        if (c > SLOT - 1) atomicOr(&s_ovf, 1);
        cnts[tid] = c;
    }
    __syncthreads();
    if (tid == 0) {
        int o = 0;
        for (int s = 0; s < 64; ++s) { offs[s] = o; o += cnts[s]; }
        s_n = o;
    }
    __syncthreads();

    int n = s_n;
    if (!s_ovf && n >= Kt && n <= CANDMAX) {
        // fast path: gather candidates from per-block slots (L2-hot)
        for (int s = 0; s < 64; ++s) {
            int c = cnts[s], o = offs[s];
            const unsigned long long* cb =
                cand + (size_t)((b << 6) + s) * SLOT + 1;
            for (int i = tid; i < c; i += 256) keys[o + i] = cb[i];
        }
        __syncthreads();
    } else {
        // ---- exact fallback: hist -> threshold -> compact, in-block ----
        for (int i = tid; i < NBIN; i += 256) lh[i] = 0;
        __syncthreads();
        const float4* src = (const float4*)(score + (size_t)b * DHW);
        for (int i = tid; i < DHW / 4; i += 256) {
            float4 v = src[i];
            atomicAdd(&lh[f2sortable(v.x) >> 20], 1);
            atomicAdd(&lh[f2sortable(v.y) >> 20], 1);
            atomicAdd(&lh[f2sortable(v.z) >> 20], 1);
            atomicAdd(&lh[f2sortable(v.w) >> 20], 1);
        }
        __syncthreads();
        {
            int base = NBIN - 16 - 16 * tid;
            int s = 0;
            #pragma unroll
            for (int i = 0; i < 16; ++i) s += lh[base + i];
            partial[tid] = s;
        }
        __syncthreads();
        if (tid == 0) {
            int cum = 0, T = 0;
            for (int j = 0; j < 256; ++j) {
                if (cum + partial[j] >= Kt) {
                    int bb = NBIN - 1 - 16 * j;
                    for (int i = 0; i < 16; ++i) {
                        cum += lh[bb - i];
                        if (cum >= Kt) { T = bb - i; break; }
                    }
                    break;
                }
                cum += partial[j];
            }
            s_thr = T;
        }
        __syncthreads();
        const unsigned thr = (unsigned)s_thr;
        for (int i = tid; i < DHW / 4; i += 256) {
            float4 v = src[i];
            float vals[4] = {v.x, v.y, v.z, v.w};
            #pragma unroll
            for (int l = 0; l < 4; ++l) {
                unsigned u = f2sortable(vals[l]);
                if ((u >> 20) >= thr) {
                    int pos = atomicAdd(&s_cnt, 1);
                    if (pos < CANDMAX)
                        keys[pos] = ((unsigned long long)u << 32) |
                                    (0xFFFFFFFFu - (unsigned)(4 * i + l));
                }
            }
        }
        __syncthreads();
        n = s_cnt;
        if (n > CANDMAX) n = CANDMAX;
    }

    // rank selection: keys are unique (idx embedded) -> ranks unique; n >= 64
    for (int i = tid; i < n; i += 256) {
        unsigned long long k = keys[i];
        int r = 0;
        for (int j = 0; j < n; ++j) r += (keys[j] > k);
        if (r < Kt) win[r] = k;
    }
    __syncthreads();

    if (tid < Kt) {
        unsigned long long kk = win[tid];
        float sc = sortable2f((unsigned)(kk >> 32));
        unsigned gidx = 0xFFFFFFFFu - (unsigned)(kk & 0xFFFFFFFFu);
        int z = (int)(gidx >> 12);
        int y = (int)((gidx >> 6) & 63);
        int x = (int)(gidx & 63);
        int o = (b * Kt + tid) * 3;
        out[o + 0] = (float)z;
        out[o + 1] = (float)y;
        out[o + 2] = (float)x;
        out[OUT_SCORES + b * Kt + tid] = sc;
        sgidx[tid] = gidx;
    }
    __syncthreads();
    // spatial sort of the 64 winners: rank by gidx ascending (gidx unique)
    if (tid < Kt) {
        unsigned g = sgidx[tid];
        int r = 0;
        #pragma unroll
        for (int j = 0; j < Kt; ++j) r += (sgidx[j] < g);
        sorted_idx[b * Kt + r] = (int)((unsigned)(tid << 20) | g);
    }
}

// ---------------- Gather: masked patch average per (b,k,c) ---------------
// Round-4 form + SPATIAL ORDERING: lane = position in the spatially sorted
// winner list, so a wave's 64 addresses ascend within one channel slice
// (DRAM page/row-buffer locality). Results scatter to the original k slot.
__global__ __launch_bounds__(256) void gather_kernel(
        const float* __restrict__ fm, const int* __restrict__ sorted_idx,
        float* __restrict__ vec) {
    const int blk = blockIdx.x;        // Bn*64 = 256
    const int b   = blk >> 6;
    const int cg  = blk & 63;
    const int tid = threadIdx.x;
    const int k   = tid & 63;          // lane = sorted position
    const int c   = cg * 4 + (tid >> 6);

    const int e     = sorted_idx[b * Kt + k];
    const int idx   = e & 0xFFFFF;     // gidx (17 bits)
    const int korig = ((unsigned)e) >> 20;
    const int z = idx >> 12;
    const int y = (idx >> 6) & 63;
    const int x = idx & 63;
    const int z0 = max(z - 2, 0), y0 = max(y - 2, 0), x0 = max(x - 2, 0);
    const int nz = min(5, Dn - z0), ny = min(5, Hn - y0), nx = min(5, Wn - x0);
    const int xe = x0 + nx;            // <= 64
    const int a0 = x0 & ~3;
    const bool need2 = (a0 + 4) < xe;

    float m[8];
    #pragma unroll
    for (int j = 0; j < 8; ++j) {
        int e2 = a0 + j;
        m[j] = (e2 >= x0 && e2 < xe) ? 1.f : 0.f;
    }

    const float* base = fm + ((size_t)(b * Cn + c)) * DHW
                           + (size_t)z0 * HW + (size_t)y0 * Wn;
    float s = 0.f;
    #pragma unroll
    for (int iz = 0; iz < 5; ++iz) {
        #pragma unroll
        for (int iy = 0; iy < 5; ++iy) {
            if (iz < nz && iy < ny) {          // per-lane predication
                const float* row = base + iz * HW + iy * Wn;
                float4 v0 = *(const float4*)(row + a0);
                s = fmaf(v0.x, m[0], s);
                s = fmaf(v0.y, m[1], s);
                s = fmaf(v0.z, m[2], s);
                s = fmaf(v0.w, m[3], s);
                if (need2) {
                    float4 v1 = *(const float4*)(row + a0 + 4);
                    s = fmaf(v1.x, m[4], s);
                    s = fmaf(v1.y, m[5], s);
                    s = fmaf(v1.z, m[6], s);
                    s = fmaf(v1.w, m[7], s);
                }
            }
        }
    }
    vec[((size_t)(b * Kt + korig) << 8) + c] = s / (float)(nz * ny * nx);
}

// ---------------- GEMV: feature = vec @ Wp^T + b --------------------------
__global__ __launch_bounds__(256) void gemv_kernel(
        const float* __restrict__ vec, const float* __restrict__ Wp,
        const float* __restrict__ bias, float* __restrict__ out) {
    const int p   = blockIdx.x;        // PROJ
    const int tid = threadIdx.x;       // 256
    const float4* w4 = (const float4*)(Wp + (size_t)p * VECLEN);

    float acc[Bn] = {0.f, 0.f, 0.f, 0.f};
    for (int i = tid; i < VECLEN / 4; i += 256) {
        float4 wv = w4[i];
        #pragma unroll
        for (int bb = 0; bb < Bn; ++bb) {
            float4 vv = ((const float4*)(vec + bb * VECLEN))[i];
            acc[bb] += wv.x * vv.x + wv.y * vv.y + wv.z * vv.z + wv.w * vv.w;
        }
    }

    __shared__ float red[4][Bn];
    const int lane = tid & 63, wave = tid >> 6;
    #pragma unroll
    for (int bb = 0; bb < Bn; ++bb) {
        float v = acc[bb];
        #pragma unroll
        for (int off = 32; off > 0; off >>= 1) v += __shfl_down(v, off, 64);
        if (lane == 0) red[wave][bb] = v;
    }
    __syncthreads();
    if (tid < Bn) {
        int bb = tid;
        float t = red[0][bb] + red[1][bb] + red[2][bb] + red[3][bb];
        out[OUT_FEAT + bb * PROJ + p] = t + bias[p];
    }
}

extern "C" void kernel_launch(void* const* d_in, const int* in_sizes, int n_in,
                              void* d_out, int out_size, void* d_ws, size_t ws_size,
                              hipStream_t stream) {
    const float* fm    = (const float*)d_in[0];
    const float* score = (const float*)d_in[1];
    const float* Wp    = (const float*)d_in[2];
    const float* bias  = (const float*)d_in[3];
    float* out = (float*)d_out;

    char* ws = (char*)d_ws;
    unsigned long long* cand = (unsigned long long*)(ws + WS_CAND_OFF);
    int*   sorted_idx = (int*)(ws + WS_IDX_OFF);
    float* vec        = (float*)(ws + WS_VEC_OFF);

    compact_kernel<<<Bn * 64, 256, 0, stream>>>(score, cand);
    final_kernel<<<Bn, 256, 0, stream>>>(score, cand, out, sorted_idx);
    gather_kernel<<<Bn * 64, 256, 0, stream>>>(fm, sorted_idx, vec);
    gemv_kernel<<<PROJ, 256, 0, stream>>>(vec, Wp, bias, out);
}

// Round 11
// 59.364 us; speedup vs baseline: 2.3335x; 1.1040x over previous
//
#include <hip/hip_runtime.h>
#include <hip/hip_bf16.h>

// Problem constants
#define Bn   4
#define Cn   256
#define Dn   32
#define Hn   64
#define Wn   64
#define Kt   64          // top-k
#define PROJ 512
#define DHW  (Dn*Hn*Wn)  // 131072
#define HW   (Hn*Wn)     // 4096
#define VECLEN (Kt*Cn)   // 16384 per batch

#define NBIN    4096     // fallback histogram bins (top 12 sortable bits)
#define CANDMAX 4096     // candidate cap (LDS)
#define SLOT    128      // per-compact-block slot stride (u64): [0]=count, 127 usable
#define STATIC_THR 3.0f  // scores ~ N(0,1); top-64/131072 is ~3.24 sigma.
                         // >3.0 keeps ~177/batch. If ever wrong (any slot >127
                         // cands, or total <64 or >4096), each gather block
                         // recomputes exactly -- correctness never depends on it.

// ---- workspace layout (bytes) ----
#define WS_CAND_OFF 0            // u64 cand[Bn*64][SLOT] = 256 KB
#define WS_VEC_OFF  (260*1024)   // float vec[Bn][VECLEN] = 256 KB

// ---- d_out layout (float32 elements) ----
#define OUT_SCORES 768
#define OUT_FEAT   1024

__device__ __forceinline__ unsigned f2sortable(float f) {
    unsigned u = __float_as_uint(f);
    return (u & 0x80000000u) ? ~u : (u | 0x80000000u);
}
__device__ __forceinline__ float sortable2f(unsigned u) {
    unsigned orig = (u & 0x80000000u) ? (u & 0x7FFFFFFFu) : ~u;
    return __uint_as_float(orig);
}

// ---------------- Pass 1: static-threshold compact into per-block slots --
// grid = Bn*64 = 256 blocks x 256 threads; block owns slot region [blk*SLOT].
// Every block writes its count word unconditionally -> no pre-zero needed.
__global__ __launch_bounds__(256) void compact_kernel(
        const float* __restrict__ score, unsigned long long* __restrict__ cand) {
    __shared__ unsigned long long lc[SLOT - 1];
    __shared__ int lcnt;
    const int blk = blockIdx.x;
    const int b   = blk >> 6;
    const int sub = blk & 63;
    const int tid = threadIdx.x;
    if (tid == 0) lcnt = 0;
    __syncthreads();

    const unsigned thr = f2sortable(STATIC_THR);
    const float4* src = (const float4*)(score + (size_t)b * DHW) + sub * 512;
    #pragma unroll
    for (int i = tid; i < 512; i += 256) {
        float4 v = src[i];
        unsigned gbase = (unsigned)((sub * 512 + i) * 4);
        float vals[4] = {v.x, v.y, v.z, v.w};
        #pragma unroll
        for (int l = 0; l < 4; ++l) {
            unsigned u = f2sortable(vals[l]);
            if (u >= thr) {
                int pos = atomicAdd(&lcnt, 1);
                if (pos < SLOT - 1)
                    lc[pos] = ((unsigned long long)u << 32) |
                              (0xFFFFFFFFu - (gbase + l));
            }
        }
    }
    __syncthreads();

    unsigned long long* cb = cand + (size_t)blk * SLOT;
    int n = lcnt;
    if (n > SLOT - 1) n = SLOT;          // SLOT = overflow marker
    if (tid == 0) cb[0] = (unsigned long long)n;
    int m = (n > SLOT - 1) ? (SLOT - 1) : n;
    for (int i = tid; i < m; i += 256) cb[1 + i] = lc[i];
}

// ---------------- Pass 2 (fused): per-block top-64 + gather ---------------
// grid = Bn*64 = 256 blocks x 256 threads. Each block redundantly recomputes
// the top-64 from the slot buffer (L2-hot, ~1us prologue, deterministic),
// spatially sorts the winners, then gathers its 4 channels. Blocks with
// cg==0 also emit centers/scores. Exact fallback if the threshold guess
// ever fails (slot overflow, n<64, or n>CANDMAX).
__global__ __launch_bounds__(256) void gather_kernel(
        const float* __restrict__ fm, const float* __restrict__ score,
        const unsigned long long* __restrict__ cand,
        float* __restrict__ out, float* __restrict__ vec) {
    __shared__ unsigned long long keys[CANDMAX];   // 32 KB
    __shared__ unsigned long long win[Kt];
    __shared__ unsigned sgidx[Kt];
    __shared__ int ssorted[Kt];
    __shared__ int lh[NBIN];                       // 16 KB (fallback only)
    __shared__ int partial[256];
    __shared__ int s_cnt, s_thr, s_ovf;
    const int blk = blockIdx.x;        // Bn*64
    const int b   = blk >> 6;
    const int cg  = blk & 63;
    const int tid = threadIdx.x;

    if (tid == 0) { s_cnt = 0; s_ovf = 0; }
    __syncthreads();

    // parallel slot copy: thread s<64 appends slot s's keys (order-free)
    if (tid < 64) {
        const unsigned long long* cb = cand + (size_t)((b << 6) + tid) * SLOT;
        int c = (int)cb[0];
        if (c > SLOT - 1) {
            atomicOr(&s_ovf, 1);
        } else if (c > 0) {
            int o = atomicAdd(&s_cnt, c);
            for (int i = 0; i < c; ++i)
                if (o + i < CANDMAX) keys[o + i] = cb[1 + i];
        }
    }
    __syncthreads();

    int n = s_cnt;
    if (s_ovf || n < Kt || n > CANDMAX) {
        // ---- exact fallback: hist -> threshold -> compact, in-block ----
        __syncthreads();
        for (int i = tid; i < NBIN; i += 256) lh[i] = 0;
        if (tid == 0) s_cnt = 0;
        __syncthreads();
        const float4* src = (const float4*)(score + (size_t)b * DHW);
        for (int i = tid; i < DHW / 4; i += 256) {
            float4 v = src[i];
            atomicAdd(&lh[f2sortable(v.x) >> 20], 1);
            atomicAdd(&lh[f2sortable(v.y) >> 20], 1);
            atomicAdd(&lh[f2sortable(v.z) >> 20], 1);
            atomicAdd(&lh[f2sortable(v.w) >> 20], 1);
        }
        __syncthreads();
        {
            int base = NBIN - 16 - 16 * tid;
            int s = 0;
            #pragma unroll
            for (int i = 0; i < 16; ++i) s += lh[base + i];
            partial[tid] = s;
        }
        __syncthreads();
        if (tid == 0) {
            int cum = 0, T = 0;
            for (int j = 0; j < 256; ++j) {
                if (cum + partial[j] >= Kt) {
                    int bb = NBIN - 1 - 16 * j;
                    for (int i = 0; i < 16; ++i) {
                        cum += lh[bb - i];
                        if (cum >= Kt) { T = bb - i; break; }
                    }
                    break;
                }
                cum += partial[j];
            }
            s_thr = T;
        }
        __syncthreads();
        const unsigned thr = (unsigned)s_thr;
        for (int i = tid; i < DHW / 4; i += 256) {
            float4 v = src[i];
            float vals[4] = {v.x, v.y, v.z, v.w};
            #pragma unroll
            for (int l = 0; l < 4; ++l) {
                unsigned u = f2sortable(vals[l]);
                if ((u >> 20) >= thr) {
                    int pos = atomicAdd(&s_cnt, 1);
                    if (pos < CANDMAX)
                        keys[pos] = ((unsigned long long)u << 32) |
                                    (0xFFFFFFFFu - (unsigned)(4 * i + l));
                }
            }
        }
        __syncthreads();
        n = s_cnt;
        if (n > CANDMAX) n = CANDMAX;
    }

    // rank selection: keys unique (idx embedded) -> unique ranks; n >= 64
    for (int i = tid; i < n; i += 256) {
        unsigned long long k = keys[i];
        int r = 0;
        for (int j = 0; j < n; ++j) r += (keys[j] > k);
        if (r < Kt) win[r] = k;
    }
    __syncthreads();

    if (tid < Kt) {
        unsigned long long kk = win[tid];
        unsigned gidx = 0xFFFFFFFFu - (unsigned)(kk & 0xFFFFFFFFu);
        sgidx[tid] = gidx;
        if (cg == 0) {                     // 4 blocks emit centers/scores
            float sc = sortable2f((unsigned)(kk >> 32));
            int z = (int)(gidx >> 12);
            int y = (int)((gidx >> 6) & 63);
            int x = (int)(gidx & 63);
            int o = (b * Kt + tid) * 3;
            out[o + 0] = (float)z;
            out[o + 1] = (float)y;
            out[o + 2] = (float)x;
            out[OUT_SCORES + b * Kt + tid] = sc;
        }
    }
    __syncthreads();
    // spatial sort of winners: rank by gidx ascending (gidx unique)
    if (tid < Kt) {
        unsigned g = sgidx[tid];
        int r = 0;
        #pragma unroll
        for (int j = 0; j < Kt; ++j) r += (sgidx[j] < g);
        ssorted[r] = (int)((unsigned)(tid << 20) | g);
    }
    __syncthreads();

    // ---------------- gather: lane = sorted position, deep MLP ----------
    {
        const int k = tid & 63;            // lane = sorted position
        const int c = cg * 4 + (tid >> 6);

        const int e     = ssorted[k];
        const int idx   = e & 0xFFFFF;     // gidx (17 bits)
        const int korig = ((unsigned)e) >> 20;
        const int z = idx >> 12;
        const int y = (idx >> 6) & 63;
        const int x = idx & 63;
        const int z0 = max(z - 2, 0), y0 = max(y - 2, 0), x0 = max(x - 2, 0);
        const int nz = min(5, Dn - z0), ny = min(5, Hn - y0), nx = min(5, Wn - x0);
        const int xe = x0 + nx;            // <= 64
        const int a0 = x0 & ~3;
        const bool need2 = (a0 + 4) < xe;

        float m[8];
        #pragma unroll
        for (int j = 0; j < 8; ++j) {
            int e2 = a0 + j;
            m[j] = (e2 >= x0 && e2 < xe) ? 1.f : 0.f;
        }

        const float* base = fm + ((size_t)(b * Cn + c)) * DHW
                               + (size_t)z0 * HW + (size_t)y0 * Wn;
        float s = 0.f;
        #pragma unroll
        for (int iz = 0; iz < 5; ++iz) {
            #pragma unroll
            for (int iy = 0; iy < 5; ++iy) {
                if (iz < nz && iy < ny) {          // per-lane predication
                    const float* row = base + iz * HW + iy * Wn;
                    float4 v0 = *(const float4*)(row + a0);
                    s = fmaf(v0.x, m[0], s);
                    s = fmaf(v0.y, m[1], s);
                    s = fmaf(v0.z, m[2], s);
                    s = fmaf(v0.w, m[3], s);
                    if (need2) {
                        float4 v1 = *(const float4*)(row + a0 + 4);
                        s = fmaf(v1.x, m[4], s);
                        s = fmaf(v1.y, m[5], s);
                        s = fmaf(v1.z, m[6], s);
                        s = fmaf(v1.w, m[7], s);
                    }
                }
            }
        }
        vec[((size_t)(b * Kt + korig) << 8) + c] = s / (float)(nz * ny * nx);
    }
}

// ---------------- GEMV: feature = vec @ Wp^T + b, 2 rows per block -------
__global__ __launch_bounds__(256) void gemv_kernel(
        const float* __restrict__ vec, const float* __restrict__ Wp,
        const float* __restrict__ bias, float* __restrict__ out) {
    __shared__ float gred[4][8];
    const int p0  = blockIdx.x * 2;    // 256 blocks -> rows p0, p0+1
    const int tid = threadIdx.x;       // 256
    const float4* w0 = (const float4*)(Wp + (size_t)p0 * VECLEN);
    const float4* w1 = (const float4*)(Wp + (size_t)(p0 + 1) * VECLEN);

    float acc0[Bn] = {0.f, 0.f, 0.f, 0.f};
    float acc1[Bn] = {0.f, 0.f, 0.f, 0.f};
    for (int i = tid; i < VECLEN / 4; i += 256) {
        float4 a = w0[i];
        float4 c = w1[i];
        #pragma unroll
        for (int bb = 0; bb < Bn; ++bb) {
            float4 vv = ((const float4*)(vec + bb * VECLEN))[i];
            acc0[bb] += a.x * vv.x + a.y * vv.y + a.z * vv.z + a.w * vv.w;
            acc1[bb] += c.x * vv.x + c.y * vv.y + c.z * vv.z + c.w * vv.w;
        }
    }

    const int lane = tid & 63, wave = tid >> 6;
    #pragma unroll
    for (int bb = 0; bb < Bn; ++bb) {
        float v0 = acc0[bb], v1 = acc1[bb];
        #pragma unroll
        for (int off = 32; off > 0; off >>= 1) {
            v0 += __shfl_down(v0, off, 64);
            v1 += __shfl_down(v1, off, 64);
        }
        if (lane == 0) { gred[wave][bb * 2] = v0; gred[wave][bb * 2 + 1] = v1; }
    }
    __syncthreads();
    if (tid < 8) {
        int bb = tid >> 1, q = tid & 1;
        float t = gred[0][tid] + gred[1][tid] + gred[2][tid] + gred[3][tid];
        out[OUT_FEAT + bb * PROJ + p0 + q] = t + bias[p0 + q];
    }
}

extern "C" void kernel_launch(void* const* d_in, const int* in_sizes, int n_in,
                              void* d_out, int out_size, void* d_ws, size_t ws_size,
                              hipStream_t stream) {
    const float* fm    = (const float*)d_in[0];
    const float* score = (const float*)d_in[1];
    const float* Wp    = (const float*)d_in[2];
    const float* bias  = (const float*)d_in[3];
    float* out = (float*)d_out;

    char* ws = (char*)d_ws;
    unsigned long long* cand = (unsigned long long*)(ws + WS_CAND_OFF);
    float* vec = (float*)(ws + WS_VEC_OFF);

    compact_kernel<<<Bn * 64, 256, 0, stream>>>(score, cand);
    gather_kernel<<<Bn * 64, 256, 0, stream>>>(fm, score, cand, out, vec);
    gemv_kernel<<<PROJ / 2, 256, 0, stream>>>(vec, Wp, bias, out);
}